// Round 17
// baseline (181.333 us; speedup 1.0000x reference)
//
#include <hip/hip_runtime.h>
#include <hip/hip_bf16.h>
#include <stdint.h>

#define B_ 4
#define S_ 2048
#define D_ 1024
#define H_ 16
#define HD_ 64
#define TD_ 1024

typedef __attribute__((ext_vector_type(4))) float f32x4;
typedef __attribute__((ext_vector_type(8))) __bf16 bf16x8;
typedef __attribute__((ext_vector_type(4))) __bf16 bf16x4;

__device__ __forceinline__ f32x4 mfma_16x16x32(bf16x8 a, bf16x8 b, f32x4 c) {
  return __builtin_amdgcn_mfma_f32_16x16x32_bf16(a, b, c, 0, 0, 0);
}

__device__ __forceinline__ float fexp2(float x) {
#if __has_builtin(__builtin_amdgcn_exp2f)
  return __builtin_amdgcn_exp2f(x);
#else
  return exp2f(x);
#endif
}

// packed f32x2 -> bf16x2 (RNE), single instruction (T12)
__device__ __forceinline__ uint32_t pkbf16(float lo, float hi) {
  uint32_t r;
  asm("v_cvt_pk_bf16_f32 %0, %1, %2" : "=v"(r) : "v"(lo), "v"(hi));
  return r;
}

// async global->LDS, 16B per lane, offset ALWAYS 0 (proven path).
// LDS dest must be wave-uniform base; HW adds lane*16.
__device__ __forceinline__ void gload16(const void* g, void* l) {
  __builtin_amdgcn_global_load_lds(
      (const __attribute__((address_space(1))) uint32_t*)(uintptr_t)g,
      (__attribute__((address_space(3))) uint32_t*)(uintptr_t)l,
      16, 0, 0);
}

// XCD-aware bijective swizzle of a flat block id (requires nwg % 8 == 0).
__device__ __forceinline__ int xcd_swz(int flat, int nwg) {
  return (flat & 7) * (nwg >> 3) + (flat >> 3);
}

// ---------------- conversions ----------------

__global__ __launch_bounds__(256) void conv_x_kernel(const float* __restrict__ in,
                                                     __bf16* __restrict__ out) {
  size_t i = ((size_t)blockIdx.x * 256 + threadIdx.x) * 8;
  float4 a = *(const float4*)(in + i);
  float4 b = *(const float4*)(in + i + 4);
  bf16x8 o;
  o[0] = (__bf16)a.x; o[1] = (__bf16)a.y; o[2] = (__bf16)a.z; o[3] = (__bf16)a.w;
  o[4] = (__bf16)b.x; o[5] = (__bf16)b.y; o[6] = (__bf16)b.z; o[7] = (__bf16)b.w;
  *(bf16x8*)(out + i) = o;
}

// transpose 1024x1024 f32 [K][N] -> bf16 [N][K] with scale; z selects which weight
__global__ __launch_bounds__(256) void wconv4_kernel(
    const float* __restrict__ w0, const float* __restrict__ w1,
    const float* __restrict__ w2, const float* __restrict__ w3,
    __bf16* __restrict__ o0, __bf16* __restrict__ o1,
    __bf16* __restrict__ o2, __bf16* __restrict__ o3, float scale0) {
  const float* in; __bf16* out; float scale;
  switch (blockIdx.z) {
    case 0: in = w0; out = o0; scale = scale0; break;
    case 1: in = w1; out = o1; scale = 1.0f; break;
    case 2: in = w2; out = o2; scale = 1.0f; break;
    default: in = w3; out = o3; scale = 1.0f; break;
  }
  __shared__ float t[64][65];
  const int bx = blockIdx.x * 64;  // N base
  const int by = blockIdx.y * 64;  // K base
  for (int e = threadIdx.x; e < 4096; e += 256) {
    int r = e >> 6, c = e & 63;
    t[r][c] = in[(size_t)(by + r) * 1024 + bx + c];
  }
  __syncthreads();
  for (int e = threadIdx.x; e < 4096; e += 256) {
    int r = e >> 6, c = e & 63;
    out[(size_t)(bx + r) * 1024 + by + c] = (__bf16)(t[c][r] * scale);
  }
}

// ---------------- QKV GEMM: 128(M) x 256(N) tile, 3-slot K-half ring ----------
// (frozen from round 14 — validated)

#define STG3(SLOT)                                                      \
  gload16(srcA, dstA + (SLOT) * 8192);                                  \
  gload16(srcB, dstB + (SLOT) * 16384);                                 \
  gload16(srcB + 131072, dstB + (SLOT) * 16384 + 8192);                 \
  srcA += 32; srcB += 32;

#define COMPUTE_HALF(SLOT)                                              \
  {                                                                     \
    bf16x8 afr[4], bb[4];                                               \
    _Pragma("unroll") for (int mi = 0; mi < 4; ++mi)                    \
      afr[mi] = *(const bf16x8*)(aptr + (SLOT) * 8192 + mi * 1024);     \
    _Pragma("unroll") for (int ni = 0; ni < 4; ++ni)                    \
      bb[ni] = *(const bf16x8*)(bptr + (SLOT) * 16384 + ni * 1024);     \
    __builtin_amdgcn_s_setprio(1);                                      \
    _Pragma("unroll") for (int mi = 0; mi < 4; ++mi)                    \
      _Pragma("unroll") for (int ni = 0; ni < 4; ++ni)                  \
        acc[mi][ni] = mfma_16x16x32(afr[mi], bb[ni], acc[mi][ni]);      \
    __builtin_amdgcn_s_setprio(0);                                      \
  }

#define BAR_LGKM  asm volatile("s_waitcnt lgkmcnt(0)\n\ts_barrier" ::: "memory")
#define BAR_VM(N) asm volatile("s_waitcnt vmcnt(" #N ")\n\ts_barrier" ::: "memory")
#define BAR_VL(N) asm volatile("s_waitcnt vmcnt(" #N ") lgkmcnt(0)\n\ts_barrier" ::: "memory")

__global__ __launch_bounds__(512, 4) void gemm_qkv3(
    const __bf16* __restrict__ A, const __bf16* __restrict__ Bt,
    const float* __restrict__ bq, const float* __restrict__ bk,
    const float* __restrict__ bv, __bf16* __restrict__ Qout,
    __bf16* __restrict__ Kout, __bf16* __restrict__ Vout, float qscale) {
  __shared__ char SM[73728];  // A: [3][8K] at 0; B: [3][16K] at 24576
  const int tid = threadIdx.x, lane = tid & 63, wid = tid >> 6;
  const int lrow = lane & 15, g = lane >> 4;
  const int wm = wid >> 2, wn = wid & 3;
  const int flat = blockIdx.y * 12 + blockIdx.x;
  const int swz = xcd_swz(flat, 768);
  const int n0 = (swz % 12) * 256, m0 = (swz / 12) * 128;

  f32x4 acc[4][4];
  const f32x4 zero = {0.f, 0.f, 0.f, 0.f};
#pragma unroll
  for (int i = 0; i < 4; ++i)
#pragma unroll
    for (int j = 0; j < 4; ++j) acc[i][j] = zero;

  const int r0 = tid >> 2, c0 = tid & 3;
  const int csw = c0 ^ ((r0 >> 1) & 3);
  const __bf16* srcA = A + (size_t)(m0 + r0) * 1024 + csw * 8;
  const __bf16* srcB = Bt + (size_t)(n0 + r0) * 1024 + csw * 8;
  char* dstA = SM + wid * 1024;
  char* dstB = SM + 24576 + wid * 1024;

  const int sw = (lrow >> 1) & 3;
  const char* aptr = SM + (wm * 64 + lrow) * 64 + ((g ^ sw) << 4);
  const char* bptr = SM + 24576 + (wn * 64 + lrow) * 64 + ((g ^ sw) << 4);

  STG3(0)
  STG3(1)
  asm volatile("s_waitcnt vmcnt(3)\n\ts_barrier" ::: "memory");

  for (int it = 0; it < 10; ++it) {
    STG3(2)
    COMPUTE_HALF(0)
    BAR_VL(3);
    STG3(0)
    COMPUTE_HALF(1)
    BAR_VL(3);
    STG3(1)
    COMPUTE_HALF(2)
    BAR_VL(3);
  }
  COMPUTE_HALF(0)
  BAR_VL(0);
  COMPUTE_HALF(1)

  const int sel = n0 >> 10;  // 0=Q, 1=K, 2=V
  if (sel < 2) {
    const float* bias = sel ? bk : bq;
    const float bsc = sel ? 1.0f : qscale;
    __bf16* Out = sel ? Kout : Qout;
#pragma unroll
    for (int mi = 0; mi < 4; ++mi) {
#pragma unroll
      for (int ni = 0; ni < 4; ++ni) {
        const int mbase = m0 + wm * 64 + mi * 16 + g * 4;
        const int nloc = (n0 & 1023) + wn * 64 + ni * 16 + lrow;
        const float bvc = bias[nloc] * bsc;
        const int h = nloc >> 6, hd = nloc & 63;
#pragma unroll
        for (int r = 0; r < 4; ++r) {
          const int m = mbase + r;
          const int b = m >> 11, s = m & 2047;
          Out[((size_t)(b * H_ + h) * S_ + s) * HD_ + hd] = (__bf16)(acc[mi][ni][r] + bvc);
        }
      }
    }
  } else {
#pragma unroll
    for (int mi = 0; mi < 4; ++mi) {
#pragma unroll
      for (int ni = 0; ni < 4; ++ni) {
        const int mbase = m0 + wm * 64 + mi * 16 + g * 4;
        const int t = (n0 & 1023) + wn * 64 + ni * 16 + lrow;
        const float bvc = bv[t];
        bf16x4 w;
#pragma unroll
        for (int r = 0; r < 4; ++r) w[r] = (__bf16)(acc[mi][ni][r] + bvc);
        *(bf16x4*)(Vout + (size_t)t * (B_ * S_) + mbase) = w;
      }
    }
  }
}

// ---------------- output projection: 128x128 tile, 256 thr, 2-slot ring --------
// (frozen from round 13)

#define STG_O(SLOT, KOFF)                                               \
  gload16(srcA + (KOFF), dstA + (SLOT) * 8192);                         \
  gload16(srcA + 65536 + (KOFF), dstA + (SLOT) * 8192 + 4096);          \
  gload16(srcB + (KOFF), dstB + (SLOT) * 8192);                         \
  gload16(srcB + 65536 + (KOFF), dstB + (SLOT) * 8192 + 4096);

#define COMPUTE_O(SLOT)                                                 \
  {                                                                     \
    bf16x8 afr[4], bb[4];                                               \
    _Pragma("unroll") for (int mi = 0; mi < 4; ++mi)                    \
      afr[mi] = *(const bf16x8*)(aptr + (SLOT) * 8192 + mi * 1024);     \
    _Pragma("unroll") for (int ni = 0; ni < 4; ++ni)                    \
      bb[ni] = *(const bf16x8*)(bptr + (SLOT) * 8192 + ni * 1024);      \
    __builtin_amdgcn_s_setprio(1);                                      \
    _Pragma("unroll") for (int mi = 0; mi < 4; ++mi)                    \
      _Pragma("unroll") for (int ni = 0; ni < 4; ++ni)                  \
        acc[mi][ni] = mfma_16x16x32(afr[mi], bb[ni], acc[mi][ni]);      \
    __builtin_amdgcn_s_setprio(0);                                      \
  }

__global__ __launch_bounds__(256, 4) void gemm_out_ring(
    const __bf16* __restrict__ A, const __bf16* __restrict__ Bt,
    const float* __restrict__ bias, float* __restrict__ Cout) {
  __shared__ char SM[32768];  // A: [2][8K] at 0; B: [2][8K] at 16384
  const int tid = threadIdx.x, lane = tid & 63, wid = tid >> 6;
  const int lrow = lane & 15, g = lane >> 4;
  const int wm = wid >> 1, wn = wid & 1;
  const int flat = blockIdx.y * 8 + blockIdx.x;   // grid (8, 64) = 512 blocks
  const int swz = xcd_swz(flat, 512);
  const int n0 = (swz & 7) * 128, m0 = (swz >> 3) * 128;

  f32x4 acc[4][4];
  const f32x4 zero = {0.f, 0.f, 0.f, 0.f};
#pragma unroll
  for (int i = 0; i < 4; ++i)
#pragma unroll
    for (int j = 0; j < 4; ++j) acc[i][j] = zero;

  const int r0 = tid >> 2, c0 = tid & 3;
  const int csw = c0 ^ ((r0 >> 1) & 3);
  const __bf16* srcA = A + (size_t)(m0 + r0) * 1024 + csw * 8;
  const __bf16* srcB = Bt + (size_t)(n0 + r0) * 1024 + csw * 8;
  char* dstA = SM + wid * 1024;
  char* dstB = SM + 16384 + wid * 1024;

  const int sw = (lrow >> 1) & 3;
  const char* aptr = SM + (wm * 64 + lrow) * 64 + ((g ^ sw) << 4);
  const char* bptr = SM + 16384 + (wn * 64 + lrow) * 64 + ((g ^ sw) << 4);

  STG_O(0, 0)
  STG_O(1, 32)
  srcA += 64; srcB += 64;
  BAR_VM(4);

  for (int it = 0; it < 15; ++it) {
    COMPUTE_O(0)
    BAR_LGKM;
    STG_O(0, 0)
    BAR_VM(4);
    COMPUTE_O(1)
    BAR_LGKM;
    STG_O(1, 32)
    BAR_VM(4);
    srcA += 64; srcB += 64;
  }
  COMPUTE_O(0)
  BAR_LGKM;
  BAR_VM(0);
  COMPUTE_O(1)

#pragma unroll
  for (int mi = 0; mi < 4; ++mi) {
#pragma unroll
    for (int ni = 0; ni < 4; ++ni) {
      const int mbase = m0 + wm * 64 + mi * 16 + g * 4;
      const int ncol = n0 + wn * 64 + ni * 16 + lrow;
      const float bvc = bias[ncol];
#pragma unroll
      for (int r = 0; r < 4; ++r)
        Cout[(size_t)(mbase + r) * 1024 + ncol] = acc[mi][ni][r] + bvc;
    }
  }
}

// ---------------- flash attention: 4 waves x 32 q-rows + 3-slot KV ring --------
// grid 1024 blocks, XCD-swizzled. r16's fragment-reuse compute (2 q-groups/wave)
// kept byte-identical. THIS ROUND: staging ported to the counted-vmcnt 3-slot
// ring proven in all three GEMM kernels — tile t: {STG(t+2 -> slot (t+2)%3);
// compute(t from slot t%3); vmcnt(4)+lgkmcnt(0)+barrier}. The barrier retires
// exactly tile t+1's 4-load group (publish) while t+2's stays in flight — no
// more full vmcnt(0) drain per tile (the m97-class ~20% stall both r12 and r16
// shared). WAR on slot (t+2)%3 is guarded by the previous phase's lgkm-drain.
// LDS 48KB: K 3x8K at 0; V 3x8K at 24576. 3 blocks/CU.

__global__ __launch_bounds__(256, 4) void attn_kernel(
    const __bf16* __restrict__ Q, const __bf16* __restrict__ Kp,
    const __bf16* __restrict__ VT, __bf16* __restrict__ O) {
  const int flat = blockIdx.y * gridDim.x + blockIdx.x;
  const int swz = (flat & 7) * 128 + (flat >> 3);   // bijective: 1024 % 8 == 0
  const int bh = swz >> 4;
  const int q0 = (swz & 15) * 128;
  const int tid = threadIdx.x, lane = tid & 63, wid = tid >> 6;  // wid 0..3
  const int lrow = lane & 15, g = lane >> 4;
  const int s7 = lrow & 7;
  const int b = bh >> 4, h = bh & 15;

  const __bf16* Qb = Q + (size_t)bh * S_ * HD_;

  __shared__ char SMEM[49152];  // K: [3][8K] at 0; V: [3][8K] at 24576

  const int qrowA = q0 + wid * 32 + lrow;
  const int qrowB = qrowA + 16;
  const bf16x8 qf0a = *(const bf16x8*)(Qb + (size_t)qrowA * HD_ + g * 8);
  const bf16x8 qf1a = *(const bf16x8*)(Qb + (size_t)qrowA * HD_ + 32 + g * 8);
  const bf16x8 qf0b = *(const bf16x8*)(Qb + (size_t)qrowB * HD_ + g * 8);
  const bf16x8 qf1b = *(const bf16x8*)(Qb + (size_t)qrowB * HD_ + 32 + g * 8);

  bf16x8 ones;
#pragma unroll
  for (int i = 0; i < 8; ++i) ones[i] = (__bf16)1.0f;

  // staging: granule gi0 = wid*64+lane; row=gi0>>3, src chunk = (gi0&7)^(row&7)
  const int gi0 = wid * 64 + lane;
  const int row0 = gi0 >> 3, sg0 = gi0 & 7;
  const int kc0 = sg0 ^ (row0 & 7);
  const int kvoff = row0 * HD_ + kc0 * 8;
  const int vvoff = row0 * (B_ * S_) + kc0 * 8;
  const __bf16* Kt = Kp + (size_t)bh * S_ * HD_;
  const __bf16* Vt = VT + (size_t)(h * HD_) * (B_ * S_) + b * S_;
  char* kd0 = SMEM + wid * 1024;            // + slot*8192; rows 32-63 at +4096
  char* vd0 = SMEM + 24576 + wid * 1024;

  const char* addrA = SMEM + lrow * 128 + ((g ^ s7) << 4);
  const char* addrB = SMEM + lrow * 128 + (((4 + g) ^ s7) << 4);

  f32x4 laccA, laccB;
  f32x4 oaA[4], oaB[4];
  const f32x4 zero = {0.f, 0.f, 0.f, 0.f};
  const f32x4 minit = {-8.f, -8.f, -8.f, -8.f};  // softmax base folded into C-init
  laccA = zero; laccB = zero;
#pragma unroll
  for (int i = 0; i < 4; ++i) { oaA[i] = zero; oaB[i] = zero; }

  // 4-load stage of one tile into a slot (K rows 0-31, 32-63; V rows 0-31, 32-63)
  auto stage = [&](const int so) {
    gload16(Kt + kvoff, kd0 + so);
    gload16(Kt + 32 * HD_ + kvoff, kd0 + so + 4096);
    gload16(Vt + vvoff, vd0 + so);
    gload16(Vt + (size_t)32 * (B_ * S_) + vvoff, vd0 + so + 4096);
    Kt += 64 * HD_; Vt += 64;
  };

  auto compute = [&](const int so) {
    f32x4 sa[4], sb[4];
    __builtin_amdgcn_s_setprio(1);
#pragma unroll
    for (int kt = 0; kt < 4; ++kt) {
      bf16x8 kf0 = *(const bf16x8*)(addrA + so + kt * 2048);
      bf16x8 kf1 = *(const bf16x8*)(addrB + so + kt * 2048);
      f32x4 ca = minit;
      ca = mfma_16x16x32(kf0, qf0a, ca);
      ca = mfma_16x16x32(kf1, qf1a, ca);
      sa[kt] = ca;
      f32x4 cb = minit;
      cb = mfma_16x16x32(kf0, qf0b, cb);
      cb = mfma_16x16x32(kf1, qf1b, cb);
      sb[kt] = cb;
    }
    __builtin_amdgcn_s_setprio(0);

    // P = exp2(s - 8): static base, no max pass
#pragma unroll
    for (int kt = 0; kt < 4; ++kt)
#pragma unroll
      for (int r = 0; r < 4; ++r) {
        sa[kt][r] = fexp2(sa[kt][r]);
        sb[kt][r] = fexp2(sb[kt][r]);
      }

    bf16x8 pfa[2], pfb[2];
#pragma unroll
    for (int s = 0; s < 2; ++s) {
      {
        uint32_t a0 = pkbf16(sa[2 * s][0], sa[2 * s][1]);
        uint32_t a1 = pkbf16(sa[2 * s][2], sa[2 * s][3]);
        uint32_t b0 = pkbf16(sa[2 * s + 1][0], sa[2 * s + 1][1]);
        uint32_t b1 = pkbf16(sa[2 * s + 1][2], sa[2 * s + 1][3]);
        asm volatile("v_permlane32_swap_b32 %0, %1" : "+v"(a0), "+v"(b0));
        asm volatile("v_permlane32_swap_b32 %0, %1" : "+v"(a1), "+v"(b1));
        asm volatile("v_permlane16_swap_b32 %0, %1" : "+v"(a0), "+v"(b0));
        asm volatile("v_permlane16_swap_b32 %0, %1" : "+v"(a1), "+v"(b1));
        union { uint32_t u[4]; bf16x8 v; } pu;
        pu.u[0] = a0; pu.u[1] = a1; pu.u[2] = b0; pu.u[3] = b1;
        pfa[s] = pu.v;
      }
      {
        uint32_t a0 = pkbf16(sb[2 * s][0], sb[2 * s][1]);
        uint32_t a1 = pkbf16(sb[2 * s][2], sb[2 * s][3]);
        uint32_t b0 = pkbf16(sb[2 * s + 1][0], sb[2 * s + 1][1]);
        uint32_t b1 = pkbf16(sb[2 * s + 1][2], sb[2 * s + 1][3]);
        asm volatile("v_permlane32_swap_b32 %0, %1" : "+v"(a0), "+v"(b0));
        asm volatile("v_permlane32_swap_b32 %0, %1" : "+v"(a1), "+v"(b1));
        asm volatile("v_permlane16_swap_b32 %0, %1" : "+v"(a0), "+v"(b0));
        asm volatile("v_permlane16_swap_b32 %0, %1" : "+v"(a1), "+v"(b1));
        union { uint32_t u[4]; bf16x8 v; } pu;
        pu.u[0] = a0; pu.u[1] = a1; pu.u[2] = b0; pu.u[3] = b1;
        pfb[s] = pu.v;
      }
    }

    __builtin_amdgcn_s_setprio(1);
#pragma unroll
    for (int band = 0; band < 4; ++band) {
      bf16x8 vf0 = *(const bf16x8*)(addrA + 24576 + so + band * 2048);
      bf16x8 vf1 = *(const bf16x8*)(addrB + 24576 + so + band * 2048);
      oaA[band] = mfma_16x16x32(vf0, pfa[0], oaA[band]);
      oaA[band] = mfma_16x16x32(vf1, pfa[1], oaA[band]);
      oaB[band] = mfma_16x16x32(vf0, pfb[0], oaB[band]);
      oaB[band] = mfma_16x16x32(vf1, pfb[1], oaB[band]);
    }
    laccA = mfma_16x16x32(ones, pfa[0], laccA);
    laccA = mfma_16x16x32(ones, pfa[1], laccA);
    laccB = mfma_16x16x32(ones, pfb[0], laccB);
    laccB = mfma_16x16x32(ones, pfb[1], laccB);
    __builtin_amdgcn_s_setprio(0);
  };

  // ring prologue: tiles 0,1 -> slots 0,1; vmcnt(4) publishes tile 0
  stage(0);
  stage(8192);
  BAR_VM(4);

  // 10 x 3 tiles: computes 0..29, stages 2..31; publish t+1 each phase
  for (int it = 0; it < 10; ++it) {
    stage(16384); compute(0);     BAR_VL(4);
    stage(0);     compute(8192);  BAR_VL(4);
    stage(8192);  compute(16384); BAR_VL(4);
  }
  // tail: tile 30 (slot 0; drain all -> publish 31), tile 31 (slot 1)
  compute(0);
  BAR_VL(0);
  compute(8192);

  const float invA = 1.f / laccA[0];
  const float invB = 1.f / laccB[0];
  __bf16* opA = O + ((size_t)(b * S_ + qrowA)) * TD_ + h * HD_;
  __bf16* opB = O + ((size_t)(b * S_ + qrowB)) * TD_ + h * HD_;
#pragma unroll
  for (int band = 0; band < 4; ++band) {
    bf16x4 wa, wb;
#pragma unroll
    for (int r = 0; r < 4; ++r) {
      wa[r] = (__bf16)(oaA[band][r] * invA);
      wb[r] = (__bf16)(oaB[band][r] * invB);
    }
    *(bf16x4*)(opA + band * 16 + g * 4) = wa;
    *(bf16x4*)(opB + band * 16 + g * 4) = wb;
  }
}

// ---------------- launch ----------------

extern "C" void kernel_launch(void* const* d_in, const int* in_sizes, int n_in,
                              void* d_out, int out_size, void* d_ws, size_t ws_size,
                              hipStream_t stream) {
  const float* x = (const float*)d_in[0];
  const float* Wq = (const float*)d_in[1];
  const float* bq = (const float*)d_in[2];
  const float* Wk = (const float*)d_in[3];
  const float* bk = (const float*)d_in[4];
  const float* Wv = (const float*)d_in[5];
  const float* bv = (const float*)d_in[6];
  const float* Wo = (const float*)d_in[7];
  const float* bo = (const float*)d_in[8];

  char* p = (char*)d_ws;
  const size_t SZ_X = (size_t)B_ * S_ * D_ * 2;          // 16 MB
  const size_t SZ_W = (size_t)D_ * TD_ * 2;              // 2 MB
  const size_t SZ_QKV = (size_t)B_ * H_ * S_ * HD_ * 2;  // 16 MB
  __bf16* xb = (__bf16*)p;  p += SZ_X;
  __bf16* wqT = (__bf16*)p; p += SZ_W;   // wqT,wkT,wvT CONTIGUOUS -> fused Bt (3072 rows)
  __bf16* wkT = (__bf16*)p; p += SZ_W;
  __bf16* wvT = (__bf16*)p; p += SZ_W;
  __bf16* woT = (__bf16*)p; p += SZ_W;
  __bf16* Qb = (__bf16*)p;  p += SZ_QKV;
  __bf16* Kb = (__bf16*)p;  p += SZ_QKV;
  __bf16* VTb = (__bf16*)p; p += SZ_QKV;  // [t=h*64+hd][b*2048+s]
  __bf16* attn = xb;  // reuse: xb dead after QKV GEMM

  const float SCALE_Q = 0.125f * 1.4426950408889634f;  // head-dim scale * log2(e)

  conv_x_kernel<<<4096, 256, 0, stream>>>(x, xb);
  wconv4_kernel<<<dim3(16, 16, 4), 256, 0, stream>>>(Wq, Wk, Wv, Wo,
                                                     wqT, wkT, wvT, woT, SCALE_Q);

  // Fused Q+K+V projection: 128x256 tile, 3-slot K-half ring. 768 blocks.
  gemm_qkv3<<<dim3(12, 64), 512, 0, stream>>>(
      xb, wqT, bq, bk, bv, Qb, Kb, VTb, SCALE_Q);

  attn_kernel<<<dim3(16, 64), 256, 0, stream>>>(Qb, Kb, VTb, attn);

  // Output projection: 128x128 ring, 256 thr, 512 blocks (frozen from r13).
  gemm_out_ring<<<dim3(8, 64), 256, 0, stream>>>(attn, woT, bo, (float*)d_out);
}

// Round 18
// 168.409 us; speedup vs baseline: 1.0767x; 1.0767x over previous
//
#include <hip/hip_runtime.h>
#include <hip/hip_bf16.h>
#include <stdint.h>

#define B_ 4
#define S_ 2048
#define D_ 1024
#define H_ 16
#define HD_ 64
#define TD_ 1024

typedef __attribute__((ext_vector_type(4))) float f32x4;
typedef __attribute__((ext_vector_type(8))) __bf16 bf16x8;
typedef __attribute__((ext_vector_type(4))) __bf16 bf16x4;

__device__ __forceinline__ f32x4 mfma_16x16x32(bf16x8 a, bf16x8 b, f32x4 c) {
  return __builtin_amdgcn_mfma_f32_16x16x32_bf16(a, b, c, 0, 0, 0);
}

__device__ __forceinline__ float fexp2(float x) {
#if __has_builtin(__builtin_amdgcn_exp2f)
  return __builtin_amdgcn_exp2f(x);
#else
  return exp2f(x);
#endif
}

// packed f32x2 -> bf16x2 (RNE), single instruction (T12)
__device__ __forceinline__ uint32_t pkbf16(float lo, float hi) {
  uint32_t r;
  asm("v_cvt_pk_bf16_f32 %0, %1, %2" : "=v"(r) : "v"(lo), "v"(hi));
  return r;
}

// async global->LDS, 16B per lane, offset ALWAYS 0 (proven path).
// LDS dest must be wave-uniform base; HW adds lane*16.
__device__ __forceinline__ void gload16(const void* g, void* l) {
  __builtin_amdgcn_global_load_lds(
      (const __attribute__((address_space(1))) uint32_t*)(uintptr_t)g,
      (__attribute__((address_space(3))) uint32_t*)(uintptr_t)l,
      16, 0, 0);
}

// XCD-aware bijective swizzle of a flat block id (requires nwg % 8 == 0).
__device__ __forceinline__ int xcd_swz(int flat, int nwg) {
  return (flat & 7) * (nwg >> 3) + (flat >> 3);
}

// ---------------- conversions (merged: weights z<4, x slices z>=4) ----------------

__global__ __launch_bounds__(256) void conv_all_kernel(
    const float* __restrict__ x, __bf16* __restrict__ xb,
    const float* __restrict__ w0, const float* __restrict__ w1,
    const float* __restrict__ w2, const float* __restrict__ w3,
    __bf16* __restrict__ o0, __bf16* __restrict__ o1,
    __bf16* __restrict__ o2, __bf16* __restrict__ o3, float scale0) {
  if (blockIdx.z >= 4) {
    // x conversion: 4 slices x 256 blocks x 4 iters x 256 thr x 8 f32
    const int slice = blockIdx.z - 4;
    const int bid = blockIdx.y * 16 + blockIdx.x;
    const size_t base = (size_t)slice * 2097152;
#pragma unroll
    for (int it = 0; it < 4; ++it) {
      const size_t i = base + ((size_t)(it * 256 + bid) * 256 + threadIdx.x) * 8;
      float4 a = *(const float4*)(x + i);
      float4 bq4 = *(const float4*)(x + i + 4);
      bf16x8 o;
      o[0] = (__bf16)a.x; o[1] = (__bf16)a.y; o[2] = (__bf16)a.z; o[3] = (__bf16)a.w;
      o[4] = (__bf16)bq4.x; o[5] = (__bf16)bq4.y; o[6] = (__bf16)bq4.z; o[7] = (__bf16)bq4.w;
      *(bf16x8*)(xb + i) = o;
    }
    return;
  }
  const float* in; __bf16* out; float scale;
  switch (blockIdx.z) {
    case 0: in = w0; out = o0; scale = scale0; break;
    case 1: in = w1; out = o1; scale = 1.0f; break;
    case 2: in = w2; out = o2; scale = 1.0f; break;
    default: in = w3; out = o3; scale = 1.0f; break;
  }
  __shared__ float t[64][65];
  const int bx = blockIdx.x * 64;  // N base
  const int by = blockIdx.y * 64;  // K base
  for (int e = threadIdx.x; e < 4096; e += 256) {
    int r = e >> 6, c = e & 63;
    t[r][c] = in[(size_t)(by + r) * 1024 + bx + c];
  }
  __syncthreads();
  for (int e = threadIdx.x; e < 4096; e += 256) {
    int r = e >> 6, c = e & 63;
    out[(size_t)(bx + r) * 1024 + by + c] = (__bf16)(t[c][r] * scale);
  }
}

// ---------------- QKV GEMM: 128(M) x 256(N) tile, 3-slot K-half ring ----------
// (frozen from round 14 — validated)

#define STG3(SLOT)                                                      \
  gload16(srcA, dstA + (SLOT) * 8192);                                  \
  gload16(srcB, dstB + (SLOT) * 16384);                                 \
  gload16(srcB + 131072, dstB + (SLOT) * 16384 + 8192);                 \
  srcA += 32; srcB += 32;

#define COMPUTE_HALF(SLOT)                                              \
  {                                                                     \
    bf16x8 afr[4], bb[4];                                               \
    _Pragma("unroll") for (int mi = 0; mi < 4; ++mi)                    \
      afr[mi] = *(const bf16x8*)(aptr + (SLOT) * 8192 + mi * 1024);     \
    _Pragma("unroll") for (int ni = 0; ni < 4; ++ni)                    \
      bb[ni] = *(const bf16x8*)(bptr + (SLOT) * 16384 + ni * 1024);     \
    __builtin_amdgcn_s_setprio(1);                                      \
    _Pragma("unroll") for (int mi = 0; mi < 4; ++mi)                    \
      _Pragma("unroll") for (int ni = 0; ni < 4; ++ni)                  \
        acc[mi][ni] = mfma_16x16x32(afr[mi], bb[ni], acc[mi][ni]);      \
    __builtin_amdgcn_s_setprio(0);                                      \
  }

#define BAR_LGKM  asm volatile("s_waitcnt lgkmcnt(0)\n\ts_barrier" ::: "memory")
#define BAR_VM(N) asm volatile("s_waitcnt vmcnt(" #N ")\n\ts_barrier" ::: "memory")
#define BAR_VL(N) asm volatile("s_waitcnt vmcnt(" #N ") lgkmcnt(0)\n\ts_barrier" ::: "memory")

__global__ __launch_bounds__(512, 4) void gemm_qkv3(
    const __bf16* __restrict__ A, const __bf16* __restrict__ Bt,
    const float* __restrict__ bq, const float* __restrict__ bk,
    const float* __restrict__ bv, __bf16* __restrict__ Qout,
    __bf16* __restrict__ Kout, __bf16* __restrict__ Vout, float qscale) {
  __shared__ char SM[73728];  // A: [3][8K] at 0; B: [3][16K] at 24576
  const int tid = threadIdx.x, lane = tid & 63, wid = tid >> 6;
  const int lrow = lane & 15, g = lane >> 4;
  const int wm = wid >> 2, wn = wid & 3;
  const int flat = blockIdx.y * 12 + blockIdx.x;
  const int swz = xcd_swz(flat, 768);
  const int n0 = (swz % 12) * 256, m0 = (swz / 12) * 128;

  f32x4 acc[4][4];
  const f32x4 zero = {0.f, 0.f, 0.f, 0.f};
#pragma unroll
  for (int i = 0; i < 4; ++i)
#pragma unroll
    for (int j = 0; j < 4; ++j) acc[i][j] = zero;

  const int r0 = tid >> 2, c0 = tid & 3;
  const int csw = c0 ^ ((r0 >> 1) & 3);
  const __bf16* srcA = A + (size_t)(m0 + r0) * 1024 + csw * 8;
  const __bf16* srcB = Bt + (size_t)(n0 + r0) * 1024 + csw * 8;
  char* dstA = SM + wid * 1024;
  char* dstB = SM + 24576 + wid * 1024;

  const int sw = (lrow >> 1) & 3;
  const char* aptr = SM + (wm * 64 + lrow) * 64 + ((g ^ sw) << 4);
  const char* bptr = SM + 24576 + (wn * 64 + lrow) * 64 + ((g ^ sw) << 4);

  STG3(0)
  STG3(1)
  asm volatile("s_waitcnt vmcnt(3)\n\ts_barrier" ::: "memory");

  for (int it = 0; it < 10; ++it) {
    STG3(2)
    COMPUTE_HALF(0)
    BAR_VL(3);
    STG3(0)
    COMPUTE_HALF(1)
    BAR_VL(3);
    STG3(1)
    COMPUTE_HALF(2)
    BAR_VL(3);
  }
  COMPUTE_HALF(0)
  BAR_VL(0);
  COMPUTE_HALF(1)

  const int sel = n0 >> 10;  // 0=Q, 1=K, 2=V
  if (sel < 2) {
    const float* bias = sel ? bk : bq;
    const float bsc = sel ? 1.0f : qscale;
    __bf16* Out = sel ? Kout : Qout;
#pragma unroll
    for (int mi = 0; mi < 4; ++mi) {
#pragma unroll
      for (int ni = 0; ni < 4; ++ni) {
        const int mbase = m0 + wm * 64 + mi * 16 + g * 4;
        const int nloc = (n0 & 1023) + wn * 64 + ni * 16 + lrow;
        const float bvc = bias[nloc] * bsc;
        const int h = nloc >> 6, hd = nloc & 63;
#pragma unroll
        for (int r = 0; r < 4; ++r) {
          const int m = mbase + r;
          const int b = m >> 11, s = m & 2047;
          Out[((size_t)(b * H_ + h) * S_ + s) * HD_ + hd] = (__bf16)(acc[mi][ni][r] + bvc);
        }
      }
    }
  } else {
#pragma unroll
    for (int mi = 0; mi < 4; ++mi) {
#pragma unroll
      for (int ni = 0; ni < 4; ++ni) {
        const int mbase = m0 + wm * 64 + mi * 16 + g * 4;
        const int t = (n0 & 1023) + wn * 64 + ni * 16 + lrow;
        const float bvc = bv[t];
        bf16x4 w;
#pragma unroll
        for (int r = 0; r < 4; ++r) w[r] = (__bf16)(acc[mi][ni][r] + bvc);
        *(bf16x4*)(Vout + (size_t)t * (B_ * S_) + mbase) = w;
      }
    }
  }
}

// ---------------- output projection: 128x128 tile, 256 thr, 2-slot ring --------
// (frozen from round 13)

#define STG_O(SLOT, KOFF)                                               \
  gload16(srcA + (KOFF), dstA + (SLOT) * 8192);                         \
  gload16(srcA + 65536 + (KOFF), dstA + (SLOT) * 8192 + 4096);          \
  gload16(srcB + (KOFF), dstB + (SLOT) * 8192);                         \
  gload16(srcB + 65536 + (KOFF), dstB + (SLOT) * 8192 + 4096);

#define COMPUTE_O(SLOT)                                                 \
  {                                                                     \
    bf16x8 afr[4], bb[4];                                               \
    _Pragma("unroll") for (int mi = 0; mi < 4; ++mi)                    \
      afr[mi] = *(const bf16x8*)(aptr + (SLOT) * 8192 + mi * 1024);     \
    _Pragma("unroll") for (int ni = 0; ni < 4; ++ni)                    \
      bb[ni] = *(const bf16x8*)(bptr + (SLOT) * 8192 + ni * 1024);      \
    __builtin_amdgcn_s_setprio(1);                                      \
    _Pragma("unroll") for (int mi = 0; mi < 4; ++mi)                    \
      _Pragma("unroll") for (int ni = 0; ni < 4; ++ni)                  \
        acc[mi][ni] = mfma_16x16x32(afr[mi], bb[ni], acc[mi][ni]);      \
    __builtin_amdgcn_s_setprio(0);                                      \
  }

__global__ __launch_bounds__(256, 4) void gemm_out_ring(
    const __bf16* __restrict__ A, const __bf16* __restrict__ Bt,
    const float* __restrict__ bias, float* __restrict__ Cout) {
  __shared__ char SM[32768];  // A: [2][8K] at 0; B: [2][8K] at 16384
  const int tid = threadIdx.x, lane = tid & 63, wid = tid >> 6;
  const int lrow = lane & 15, g = lane >> 4;
  const int wm = wid >> 1, wn = wid & 1;
  const int flat = blockIdx.y * 8 + blockIdx.x;   // grid (8, 64) = 512 blocks
  const int swz = xcd_swz(flat, 512);
  const int n0 = (swz & 7) * 128, m0 = (swz >> 3) * 128;

  f32x4 acc[4][4];
  const f32x4 zero = {0.f, 0.f, 0.f, 0.f};
#pragma unroll
  for (int i = 0; i < 4; ++i)
#pragma unroll
    for (int j = 0; j < 4; ++j) acc[i][j] = zero;

  const int r0 = tid >> 2, c0 = tid & 3;
  const int csw = c0 ^ ((r0 >> 1) & 3);
  const __bf16* srcA = A + (size_t)(m0 + r0) * 1024 + csw * 8;
  const __bf16* srcB = Bt + (size_t)(n0 + r0) * 1024 + csw * 8;
  char* dstA = SM + wid * 1024;
  char* dstB = SM + 16384 + wid * 1024;

  const int sw = (lrow >> 1) & 3;
  const char* aptr = SM + (wm * 64 + lrow) * 64 + ((g ^ sw) << 4);
  const char* bptr = SM + 16384 + (wn * 64 + lrow) * 64 + ((g ^ sw) << 4);

  STG_O(0, 0)
  STG_O(1, 32)
  srcA += 64; srcB += 64;
  BAR_VM(4);

  for (int it = 0; it < 15; ++it) {
    COMPUTE_O(0)
    BAR_LGKM;
    STG_O(0, 0)
    BAR_VM(4);
    COMPUTE_O(1)
    BAR_LGKM;
    STG_O(1, 32)
    BAR_VM(4);
    srcA += 64; srcB += 64;
  }
  COMPUTE_O(0)
  BAR_LGKM;
  BAR_VM(0);
  COMPUTE_O(1)

#pragma unroll
  for (int mi = 0; mi < 4; ++mi) {
#pragma unroll
    for (int ni = 0; ni < 4; ++ni) {
      const int mbase = m0 + wm * 64 + mi * 16 + g * 4;
      const int ncol = n0 + wn * 64 + ni * 16 + lrow;
      const float bvc = bias[ncol];
#pragma unroll
      for (int r = 0; r < 4; ++r)
        Cout[(size_t)(mbase + r) * 1024 + ncol] = acc[mi][ni][r] + bvc;
    }
  }
}

// ---------------- flash attention: 4 waves x 32 q-rows (REVERTED to round 16) --
// grid 1024 blocks, XCD-swizzled. 4 waves own TWO 16-q groups each; every kf/vf
// LDS fragment read feeds two MFMA chains. Swapped QK^T, static-base softmax
// P=exp2(s-8) via C-init, cvt_pk+permlane redistribute, ones-row lacc, plain
// double-buffer loop with __syncthreads. r17's counted-vmcnt ring REGRESSED here
// (VGPR 64->92, LDS 32->48K, occupancy 31.9->19.6%, 77->101us): in this kernel
// occupancy beats barrier-drain elimination. Do not re-apply.

__global__ __launch_bounds__(256, 4) void attn_kernel(
    const __bf16* __restrict__ Q, const __bf16* __restrict__ Kp,
    const __bf16* __restrict__ VT, __bf16* __restrict__ O) {
  const int flat = blockIdx.y * gridDim.x + blockIdx.x;
  const int swz = (flat & 7) * 128 + (flat >> 3);   // bijective: 1024 % 8 == 0
  const int bh = swz >> 4;
  const int q0 = (swz & 15) * 128;
  const int tid = threadIdx.x, lane = tid & 63, wid = tid >> 6;  // wid 0..3
  const int lrow = lane & 15, g = lane >> 4;
  const int s7 = lrow & 7;
  const int b = bh >> 4, h = bh & 15;

  const __bf16* Qb = Q + (size_t)bh * S_ * HD_;

  __shared__ char SMEM[32768];  // K: [2][8K] at 0; V: [2][8K] at 16384

  const int qrowA = q0 + wid * 32 + lrow;
  const int qrowB = qrowA + 16;
  const bf16x8 qf0a = *(const bf16x8*)(Qb + (size_t)qrowA * HD_ + g * 8);
  const bf16x8 qf1a = *(const bf16x8*)(Qb + (size_t)qrowA * HD_ + 32 + g * 8);
  const bf16x8 qf0b = *(const bf16x8*)(Qb + (size_t)qrowB * HD_ + g * 8);
  const bf16x8 qf1b = *(const bf16x8*)(Qb + (size_t)qrowB * HD_ + 32 + g * 8);

  bf16x8 ones;
#pragma unroll
  for (int i = 0; i < 8; ++i) ones[i] = (__bf16)1.0f;

  const int gi0 = wid * 64 + lane;
  const int row0 = gi0 >> 3, sg0 = gi0 & 7;
  const int kc0 = sg0 ^ (row0 & 7);
  const int kvoff = row0 * HD_ + kc0 * 8;
  const int vvoff = row0 * (B_ * S_) + kc0 * 8;
  const __bf16* Kt = Kp + (size_t)bh * S_ * HD_;
  const __bf16* Vt = VT + (size_t)(h * HD_) * (B_ * S_) + b * S_;
  char* kd0 = SMEM + wid * 1024;
  char* vd0 = SMEM + 16384 + wid * 1024;

  const char* addrA = SMEM + lrow * 128 + ((g ^ s7) << 4);
  const char* addrB = SMEM + lrow * 128 + (((4 + g) ^ s7) << 4);

  f32x4 laccA, laccB;
  f32x4 oaA[4], oaB[4];
  const f32x4 zero = {0.f, 0.f, 0.f, 0.f};
  const f32x4 minit = {-8.f, -8.f, -8.f, -8.f};  // softmax base folded into C-init
  laccA = zero; laccB = zero;
#pragma unroll
  for (int i = 0; i < 4; ++i) { oaA[i] = zero; oaB[i] = zero; }

  gload16(Kt + kvoff, kd0); gload16(Kt + 32 * HD_ + kvoff, kd0 + 4096);
  gload16(Vt + vvoff, vd0); gload16(Vt + (size_t)32 * (B_ * S_) + vvoff, vd0 + 4096);
  Kt += 64 * HD_; Vt += 64;
  __syncthreads();

  auto stage = [&](const int bo) {
    gload16(Kt + kvoff, kd0 + bo); gload16(Kt + 32 * HD_ + kvoff, kd0 + bo + 4096);
    gload16(Vt + vvoff, vd0 + bo);
    gload16(Vt + (size_t)32 * (B_ * S_) + vvoff, vd0 + bo + 4096);
    Kt += 64 * HD_; Vt += 64;
  };

  auto compute = [&](const int bo) {
    f32x4 sa[4], sb[4];
    __builtin_amdgcn_s_setprio(1);
#pragma unroll
    for (int kt = 0; kt < 4; ++kt) {
      bf16x8 kf0 = *(const bf16x8*)(addrA + bo + kt * 2048);
      bf16x8 kf1 = *(const bf16x8*)(addrB + bo + kt * 2048);
      f32x4 ca = minit;
      ca = mfma_16x16x32(kf0, qf0a, ca);
      ca = mfma_16x16x32(kf1, qf1a, ca);
      sa[kt] = ca;
      f32x4 cb = minit;
      cb = mfma_16x16x32(kf0, qf0b, cb);
      cb = mfma_16x16x32(kf1, qf1b, cb);
      sb[kt] = cb;
    }
    __builtin_amdgcn_s_setprio(0);

#pragma unroll
    for (int kt = 0; kt < 4; ++kt)
#pragma unroll
      for (int r = 0; r < 4; ++r) {
        sa[kt][r] = fexp2(sa[kt][r]);
        sb[kt][r] = fexp2(sb[kt][r]);
      }

    bf16x8 pfa[2], pfb[2];
#pragma unroll
    for (int s = 0; s < 2; ++s) {
      {
        uint32_t a0 = pkbf16(sa[2 * s][0], sa[2 * s][1]);
        uint32_t a1 = pkbf16(sa[2 * s][2], sa[2 * s][3]);
        uint32_t b0 = pkbf16(sa[2 * s + 1][0], sa[2 * s + 1][1]);
        uint32_t b1 = pkbf16(sa[2 * s + 1][2], sa[2 * s + 1][3]);
        asm volatile("v_permlane32_swap_b32 %0, %1" : "+v"(a0), "+v"(b0));
        asm volatile("v_permlane32_swap_b32 %0, %1" : "+v"(a1), "+v"(b1));
        asm volatile("v_permlane16_swap_b32 %0, %1" : "+v"(a0), "+v"(b0));
        asm volatile("v_permlane16_swap_b32 %0, %1" : "+v"(a1), "+v"(b1));
        union { uint32_t u[4]; bf16x8 v; } pu;
        pu.u[0] = a0; pu.u[1] = a1; pu.u[2] = b0; pu.u[3] = b1;
        pfa[s] = pu.v;
      }
      {
        uint32_t a0 = pkbf16(sb[2 * s][0], sb[2 * s][1]);
        uint32_t a1 = pkbf16(sb[2 * s][2], sb[2 * s][3]);
        uint32_t b0 = pkbf16(sb[2 * s + 1][0], sb[2 * s + 1][1]);
        uint32_t b1 = pkbf16(sb[2 * s + 1][2], sb[2 * s + 1][3]);
        asm volatile("v_permlane32_swap_b32 %0, %1" : "+v"(a0), "+v"(b0));
        asm volatile("v_permlane32_swap_b32 %0, %1" : "+v"(a1), "+v"(b1));
        asm volatile("v_permlane16_swap_b32 %0, %1" : "+v"(a0), "+v"(b0));
        asm volatile("v_permlane16_swap_b32 %0, %1" : "+v"(a1), "+v"(b1));
        union { uint32_t u[4]; bf16x8 v; } pu;
        pu.u[0] = a0; pu.u[1] = a1; pu.u[2] = b0; pu.u[3] = b1;
        pfb[s] = pu.v;
      }
    }

    __builtin_amdgcn_s_setprio(1);
#pragma unroll
    for (int band = 0; band < 4; ++band) {
      bf16x8 vf0 = *(const bf16x8*)(addrA + 16384 + bo + band * 2048);
      bf16x8 vf1 = *(const bf16x8*)(addrB + 16384 + bo + band * 2048);
      oaA[band] = mfma_16x16x32(vf0, pfa[0], oaA[band]);
      oaA[band] = mfma_16x16x32(vf1, pfa[1], oaA[band]);
      oaB[band] = mfma_16x16x32(vf0, pfb[0], oaB[band]);
      oaB[band] = mfma_16x16x32(vf1, pfb[1], oaB[band]);
    }
    laccA = mfma_16x16x32(ones, pfa[0], laccA);
    laccA = mfma_16x16x32(ones, pfa[1], laccA);
    laccB = mfma_16x16x32(ones, pfb[0], laccB);
    laccB = mfma_16x16x32(ones, pfb[1], laccB);
    __builtin_amdgcn_s_setprio(0);
  };

  for (int t = 0; t < S_ / 64; t += 2) {
    stage(8192);
    compute(0);
    __syncthreads();
    if (t + 2 < S_ / 64) stage(0);
    compute(8192);
    __syncthreads();
  }

  const float invA = 1.f / laccA[0];
  const float invB = 1.f / laccB[0];
  __bf16* opA = O + ((size_t)(b * S_ + qrowA)) * TD_ + h * HD_;
  __bf16* opB = O + ((size_t)(b * S_ + qrowB)) * TD_ + h * HD_;
#pragma unroll
  for (int band = 0; band < 4; ++band) {
    bf16x4 wa, wb;
#pragma unroll
    for (int r = 0; r < 4; ++r) {
      wa[r] = (__bf16)(oaA[band][r] * invA);
      wb[r] = (__bf16)(oaB[band][r] * invB);
    }
    *(bf16x4*)(opA + band * 16 + g * 4) = wa;
    *(bf16x4*)(opB + band * 16 + g * 4) = wb;
  }
}

// ---------------- launch ----------------

extern "C" void kernel_launch(void* const* d_in, const int* in_sizes, int n_in,
                              void* d_out, int out_size, void* d_ws, size_t ws_size,
                              hipStream_t stream) {
  const float* x = (const float*)d_in[0];
  const float* Wq = (const float*)d_in[1];
  const float* bq = (const float*)d_in[2];
  const float* Wk = (const float*)d_in[3];
  const float* bk = (const float*)d_in[4];
  const float* Wv = (const float*)d_in[5];
  const float* bv = (const float*)d_in[6];
  const float* Wo = (const float*)d_in[7];
  const float* bo = (const float*)d_in[8];

  char* p = (char*)d_ws;
  const size_t SZ_X = (size_t)B_ * S_ * D_ * 2;          // 16 MB
  const size_t SZ_W = (size_t)D_ * TD_ * 2;              // 2 MB
  const size_t SZ_QKV = (size_t)B_ * H_ * S_ * HD_ * 2;  // 16 MB
  __bf16* xb = (__bf16*)p;  p += SZ_X;
  __bf16* wqT = (__bf16*)p; p += SZ_W;   // wqT,wkT,wvT CONTIGUOUS -> fused Bt (3072 rows)
  __bf16* wkT = (__bf16*)p; p += SZ_W;
  __bf16* wvT = (__bf16*)p; p += SZ_W;
  __bf16* woT = (__bf16*)p; p += SZ_W;
  __bf16* Qb = (__bf16*)p;  p += SZ_QKV;
  __bf16* Kb = (__bf16*)p;  p += SZ_QKV;
  __bf16* VTb = (__bf16*)p; p += SZ_QKV;  // [t=h*64+hd][b*2048+s]
  __bf16* attn = xb;  // reuse: xb dead after QKV GEMM

  const float SCALE_Q = 0.125f * 1.4426950408889634f;  // head-dim scale * log2(e)

  // merged conversions: z<4 weight transposes, z>=4 x-conversion slices
  conv_all_kernel<<<dim3(16, 16, 8), 256, 0, stream>>>(
      x, xb, Wq, Wk, Wv, Wo, wqT, wkT, wvT, woT, SCALE_Q);

  // Fused Q+K+V projection: 128x256 tile, 3-slot K-half ring. 768 blocks.
  gemm_qkv3<<<dim3(12, 64), 512, 0, stream>>>(
      xb, wqT, bq, bk, bv, Qb, Kb, VTb, SCALE_Q);

  attn_kernel<<<dim3(16, 64), 256, 0, stream>>>(Qb, Kb, VTb, attn);

  // Output projection: 128x128 ring, 256 thr, 512 blocks (frozen from r13).
  gemm_out_ring<<<dim3(8, 64), 256, 0, stream>>>(attn, woT, bo, (float*)d_out);
}